// Round 7
// baseline (3070.591 us; speedup 1.0000x reference)
//
#include <hip/hip_runtime.h>
#include <math.h>

#define NX 192
#define NY 192
#define NZ 96
#define NV 4
#define VOL (NZ * NY * NX)      /* 3,538,944 */
#define NTOT (NV * VOL)         /* 14,155,776 */
#define YS NX
#define ZS (NY * NX)

#define TX 48                    /* x tile: 12 interior float4 groups */
#define TY3 12                   /* y tile */
#define ZC3 48                   /* z planes per chunk (2 chunks) */
#define NG 14                    /* x groups incl halo 4: cells [-4, 52) */
#define R3A 20                   /* A rows, halo 4 */
#define R3E1 18                  /* E1 rows, halo 3 */
#define R3E2 16                  /* E2 rows, halo 2 */
#define R3E3 14                  /* E3 rows, halo 1 */

#define SLOT5(x) (((x) + 100) % 5)
#define SLOT4(x) (((x) + 100) % 4)

__device__ __forceinline__ float4 min4(float4 a, float4 b) {
    return make_float4(fminf(a.x, b.x), fminf(a.y, b.y),
                       fminf(a.z, b.z), fminf(a.w, b.w));
}
__device__ __forceinline__ float4 max4(float4 a, float4 b) {
    return make_float4(fmaxf(a.x, b.x), fmaxf(a.y, b.y),
                       fmaxf(a.z, b.z), fmaxf(a.w, b.w));
}
// per-element max of 3-windows over cells [a, b.x..b.w, c]
__device__ __forceinline__ float4 win3max(float a, float4 b, float c) {
    return make_float4(fmaxf(fmaxf(a, b.x), b.y),
                       fmaxf(fmaxf(b.x, b.y), b.z),
                       fmaxf(fmaxf(b.y, b.z), b.w),
                       fmaxf(fmaxf(b.z, b.w), c));
}

// Triple-round kernel: rounds {3j, 3j+1, 3j+2} per launch.
// Skewed pipeline, 1 barrier/step. Step z computes:
//   E1(z+1)=erode(A), E2(z-1)=erode(E1)+upd1(z-1), E3(z-3)=erode(E2)+upd2(z-3),
//   upd3(z-5) [skel write].
// All skel updates for a cell run on the SAME lane (gy = y0+lr-2) -> the
// intermediate skel values s', s'' live in 2-step-lag register chains.
// Pads: As/E1s/E2s store +inf outside volume (erode pad; dilate consumers
// substitute -inf via z/y/x masks); E3s stores -inf (dilate-only consumer).
template<bool FIRST, bool LAST>
__global__ __launch_bounds__(256, 2) void fused3_kernel(
    const float* __restrict__ pred, const float* __restrict__ target,
    const float* __restrict__ Ain, float* __restrict__ Eout,
    float* __restrict__ skel, double* __restrict__ sums)
{
    __shared__ float4 As[5][R3A][NG];
    __shared__ float4 E1s[5][R3E1][NG];
    __shared__ float4 E2s[5][R3E2][NG];
    __shared__ float4 E3s[4][R3E3][NG];

    const int tid = threadIdx.x;
    const int lr = tid >> 4;                 /* 16 row-lanes */
    const int c  = tid & 15;                 /* 16 col groups (0..13 real) */
    const int cc = (c < 14) ? c : 13;

    const int x0 = blockIdx.x * TX;
    const int y0 = blockIdx.y * TY3;
    const int v  = blockIdx.z >> 1;
    const int z0 = (blockIdx.z & 1) * ZC3;
    const int z1 = z0 + ZC3;

    const int bb = v & 1;
    const float* Av;
    if (FIRST) Av = ((v < 2) ? pred : target) + (size_t)(bb * 2 + 1) * VOL;
    else       Av = Ain + (size_t)v * VOL;
    float* Ev = Eout + (size_t)v * VOL;
    float* Sv = skel + (size_t)v * VOL;
    const float* Ov = ((v < 2) ? target : pred) + (size_t)(bb * 2 + 1) * VOL;

    const float4 PINF4 = make_float4(INFINITY, INFINITY, INFINITY, INFINITY);
    const float4 NINF4 = make_float4(-INFINITY, -INFINITY, -INFINITY, -INFINITY);
    const float4 ZERO4 = make_float4(0.f, 0.f, 0.f, 0.f);

    const bool xlo = (x0 == 0), xhi = (x0 + TX == NX);
    const int  gx = x0 - 4 + 4 * c;
    const bool gxin = (c < 14) && (gx >= 0) && (gx < NX);

    /* canonical update-lane mapping (shared by upd1/upd2/upd3) */
    const int  gyu  = y0 + lr - 2;
    const bool uactU = (lr >= 2 && lr <= 13 && c >= 1 && c <= 12);

    auto ldA = [&](int za, int r) -> float4 {
        float4 val = PINF4;
        int gy = y0 - 4 + r;
        if (za >= 0 && za < NZ && c < 14 && gy >= 0 && gy < NY &&
            gx >= 0 && gx < NX)
            val = *(const float4*)(Av + (size_t)za * ZS + gy * YS + gx);
        return val;
    };
    auto stA = [&](int za) {                 /* prologue immediate stage */
        int s = SLOT5(za);
#pragma unroll
        for (int rb = 0; rb < R3A; rb += 16) {
            int r = rb + lr;
            if (r < R3A && c < 14) As[s][r][c] = ldA(za, r);
        }
    };

    auto e1c = [&](int zp) {                 /* E1(zp), rows 0..17 */
        const int sc = SLOT5(zp), sm = SLOT5(zp - 1), sp = SLOT5(zp + 1);
        const bool hp = (zp + 1 < NZ);
#pragma unroll
        for (int rb = 0; rb < R3E1; rb += 16) {
            int re = rb + lr;
            if (re < R3E1) {
                float4 cen = As[sc][re + 1][cc];
                float4 ylo = As[sc][re][cc];
                float4 yhi = As[sc][re + 2][cc];
                float4 zlo = As[sm][re + 1][cc];
                float4 zhi = hp ? As[sp][re + 1][cc] : PINF4;
                float lw = __shfl_up(cen.w, 1);
                float rx = __shfl_down(cen.x, 1);
                if (c == 0)  lw = INFINITY;
                if (c == 13) rx = INFINITY;
                float4 m = min4(cen, make_float4(lw, cen.x, cen.y, cen.z));
                m = min4(m, make_float4(cen.y, cen.z, cen.w, rx));
                m = min4(m, min4(ylo, yhi));
                m = min4(m, min4(zlo, zhi));
                int gy = y0 - 3 + re;
                if (zp < 0 || gy < 0 || gy >= NY || !gxin) m = PINF4;
                if (c < 14) E1s[sc][re][c] = m;
            }
        }
    };

    float4 skA = ZERO4, sq1 = ZERO4, sq2 = ZERO4, sr1 = ZERO4, sr2 = ZERO4;
    float4 oA = ZERO4;
    double afd = 0.0, afs = 0.0;

    auto e2u1 = [&](int p, float4 skAv, float4& spnew) {
        if (p < 0 || p >= NZ || p > z1 + 1) return;
        const int s0 = SLOT5(p - 1), s1 = SLOT5(p), s2 = SLOT5(p + 1);
        const bool zd0 = (p - 1 >= 0);       /* E1(p-1): <0 stored PINF */
        const bool zd2 = (p + 1 < NZ);       /* E1(p+1): >=NZ never stored */
        float4 a00 = E1s[s0][lr][cc], a01 = E1s[s0][lr + 1][cc], a02 = E1s[s0][lr + 2][cc];
        float4 a10 = E1s[s1][lr][cc], a11 = E1s[s1][lr + 1][cc], a12 = E1s[s1][lr + 2][cc];
        float4 a20 = E1s[s2][lr][cc], a21 = E1s[s2][lr + 1][cc], a22 = E1s[s2][lr + 2][cc];
        {   /* erode E2(p) at cell gy = y0-2+lr */
            float4 cen = a11;
            float4 zhi = zd2 ? a21 : PINF4;
            float lw = __shfl_up(cen.w, 1);
            float rx = __shfl_down(cen.x, 1);
            if (c == 0)  lw = INFINITY;
            if (c == 13) rx = INFINITY;
            float4 m = min4(cen, make_float4(lw, cen.x, cen.y, cen.z));
            m = min4(m, make_float4(cen.y, cen.z, cen.w, rx));
            m = min4(m, min4(a10, a12));
            m = min4(m, min4(a01, zhi));
            int gy = y0 - 2 + lr;
            if (gy < 0 || gy >= NY || !gxin) m = PINF4;
            if (c < 14) E2s[s1][lr][c] = m;
        }
        if (p >= z0 && p < z1) {             /* upd1(p), same cell */
            float4 r0 = max4(zd0 ? a00 : NINF4, max4(a10, zd2 ? a20 : NINF4));
            float4 r1 = max4(zd0 ? a01 : NINF4, max4(a11, zd2 ? a21 : NINF4));
            float4 r2 = max4(zd0 ? a02 : NINF4, max4(a12, zd2 ? a22 : NINF4));
            int gy = y0 - 2 + lr;
            if (gy - 1 < 0 || gy - 1 >= NY) r0 = NINF4;
            if (gy < 0     || gy >= NY)     r1 = NINF4;
            if (gy + 1 < 0 || gy + 1 >= NY) r2 = NINF4;
            float lw0 = __shfl_up(r0.w, 1), rx0 = __shfl_down(r0.x, 1);
            float lw1 = __shfl_up(r1.w, 1), rx1 = __shfl_down(r1.x, 1);
            float lw2 = __shfl_up(r2.w, 1), rx2 = __shfl_down(r2.x, 1);
            if (xlo && c == 1)  { lw0 = -INFINITY; lw1 = -INFINITY; lw2 = -INFINITY; }
            if (xhi && c == 12) { rx0 = -INFINITY; rx1 = -INFINITY; rx2 = -INFINITY; }
            if (uactU) {
                float4 d = win3max(lw0, r0, rx0);
                d = max4(d, win3max(lw1, r1, rx1));
                d = max4(d, win3max(lw2, r2, rx2));
                float4 a = As[s1][lr + 2][cc];
                float4 s = skAv;
                float dd;
                dd = fmaxf(a.x - d.x, 0.f); s.x += fmaxf(dd - s.x * dd, 0.f);
                dd = fmaxf(a.y - d.y, 0.f); s.y += fmaxf(dd - s.y * dd, 0.f);
                dd = fmaxf(a.z - d.z, 0.f); s.z += fmaxf(dd - s.z * dd, 0.f);
                dd = fmaxf(a.w - d.w, 0.f); s.w += fmaxf(dd - s.w * dd, 0.f);
                spnew = s;
            }
        }
    };

    auto e3u2 = [&](int e, float4 sq2v, float4& srnew) {
        if (e < z0 - 1 || e > z1 || e < 0 || e >= NZ) return;
        const int s0 = SLOT5(e - 1), s1 = SLOT5(e), s2 = SLOT5(e + 1);
        const bool ze0 = (e - 1 >= 0);       /* E2(e-1) stored iff >=0 */
        const bool ze2 = (e + 1 < NZ);
        const int rm = (lr >= 1) ? lr - 1 : 0;
        const int re = (lr <= 13) ? lr : 13;
        float4 bm0 = E2s[s0][rm][cc],     bm1 = E2s[s1][rm][cc],     bm2 = E2s[s2][rm][cc];
        float4 b00 = E2s[s0][re][cc],     b10 = E2s[s1][re][cc],     b20 = E2s[s2][re][cc];
        float4 b01 = E2s[s0][re + 1][cc], b11 = E2s[s1][re + 1][cc], b21 = E2s[s2][re + 1][cc];
        float4 b02 = E2s[s0][re + 2][cc], b12 = E2s[s1][re + 2][cc], b22 = E2s[s2][re + 2][cc];
        {   /* erode E3(e) at cell gy3 = y0-1+re */
            float4 cen = b11;
            float4 zlo = ze0 ? b01 : PINF4;
            float4 zhi = ze2 ? b21 : PINF4;
            float lw = __shfl_up(cen.w, 1);
            float rx = __shfl_down(cen.x, 1);
            if (c == 0)  lw = INFINITY;
            if (c == 13) rx = INFINITY;
            float4 m = min4(cen, make_float4(lw, cen.x, cen.y, cen.z));
            m = min4(m, make_float4(cen.y, cen.z, cen.w, rx));
            m = min4(m, min4(b10, b12));
            m = min4(m, min4(zlo, zhi));
            int gy3 = y0 - 1 + re;
            if (!LAST && e >= z0 && e < z1 && lr >= 1 && lr <= 12 &&
                c >= 1 && c <= 12)
                *(float4*)(Ev + (size_t)e * ZS + gy3 * YS + gx) = m;
            float4 mst = (gy3 < 0 || gy3 >= NY || !gxin) ? NINF4 : m;
            if (lr < R3E3 && c < 14) E3s[SLOT4(e)][lr][c] = mst;
        }
        if (e >= z0 && e < z1) {             /* upd2(e) at cell gy = y0+lr-2 */
            float4 r0 = max4(ze0 ? bm0 : NINF4, max4(bm1, ze2 ? bm2 : NINF4));
            float4 r1 = max4(ze0 ? b00 : NINF4, max4(b10, ze2 ? b20 : NINF4));
            float4 r2 = max4(ze0 ? b01 : NINF4, max4(b11, ze2 ? b21 : NINF4));
            int gy = y0 + lr - 2;
            if (gy - 1 < 0 || gy - 1 >= NY) r0 = NINF4;
            if (gy < 0     || gy >= NY)     r1 = NINF4;
            if (gy + 1 < 0 || gy + 1 >= NY) r2 = NINF4;
            float lw0 = __shfl_up(r0.w, 1), rx0 = __shfl_down(r0.x, 1);
            float lw1 = __shfl_up(r1.w, 1), rx1 = __shfl_down(r1.x, 1);
            float lw2 = __shfl_up(r2.w, 1), rx2 = __shfl_down(r2.x, 1);
            if (xlo && c == 1)  { lw0 = -INFINITY; lw1 = -INFINITY; lw2 = -INFINITY; }
            if (xhi && c == 12) { rx0 = -INFINITY; rx1 = -INFINITY; rx2 = -INFINITY; }
            if (uactU) {
                float4 d = win3max(lw0, r0, rx0);
                d = max4(d, win3max(lw1, r1, rx1));
                d = max4(d, win3max(lw2, r2, rx2));
                float4 a = E1s[s1][lr + 1][cc];
                float4 s = sq2v;
                float dd;
                dd = fmaxf(a.x - d.x, 0.f); s.x += fmaxf(dd - s.x * dd, 0.f);
                dd = fmaxf(a.y - d.y, 0.f); s.y += fmaxf(dd - s.y * dd, 0.f);
                dd = fmaxf(a.z - d.z, 0.f); s.z += fmaxf(dd - s.z * dd, 0.f);
                dd = fmaxf(a.w - d.w, 0.f); s.w += fmaxf(dd - s.w * dd, 0.f);
                srnew = s;
            }
        }
    };

    auto u3 = [&](int q, float4 sr2v, float4 oAv) {
        if (q < z0 || q >= z1) return;
        const int t0 = SLOT4(q - 1), t1 = SLOT4(q), t2 = SLOT4(q + 1);
        const bool k0 = (q - 1 >= 0);
        const bool k2 = (q + 1 < NZ);
        const int rr = (lr < 2) ? 2 : ((lr > 13) ? 13 : lr);
        float4 f00 = E3s[t0][rr - 2][cc], f10 = E3s[t1][rr - 2][cc], f20 = E3s[t2][rr - 2][cc];
        float4 f01 = E3s[t0][rr - 1][cc], f11 = E3s[t1][rr - 1][cc], f21 = E3s[t2][rr - 1][cc];
        float4 f02 = E3s[t0][rr][cc],     f12 = E3s[t1][rr][cc],     f22 = E3s[t2][rr][cc];
        float4 r0 = max4(k0 ? f00 : NINF4, max4(f10, k2 ? f20 : NINF4));
        float4 r1 = max4(k0 ? f01 : NINF4, max4(f11, k2 ? f21 : NINF4));
        float4 r2 = max4(k0 ? f02 : NINF4, max4(f12, k2 ? f22 : NINF4));
        float lw0 = __shfl_up(r0.w, 1), rx0 = __shfl_down(r0.x, 1);
        float lw1 = __shfl_up(r1.w, 1), rx1 = __shfl_down(r1.x, 1);
        float lw2 = __shfl_up(r2.w, 1), rx2 = __shfl_down(r2.x, 1);
        /* E3s stores -inf pads: no x/y overrides needed */
        if (uactU) {
            float4 d = win3max(lw0, r0, rx0);
            d = max4(d, win3max(lw1, r1, rx1));
            d = max4(d, win3max(lw2, r2, rx2));
            float4 a = E2s[SLOT5(q)][lr][cc];
            float4 s = sr2v;
            float dd;
            dd = fmaxf(a.x - d.x, 0.f); s.x += fmaxf(dd - s.x * dd, 0.f);
            dd = fmaxf(a.y - d.y, 0.f); s.y += fmaxf(dd - s.y * dd, 0.f);
            dd = fmaxf(a.z - d.z, 0.f); s.z += fmaxf(dd - s.z * dd, 0.f);
            dd = fmaxf(a.w - d.w, 0.f); s.w += fmaxf(dd - s.w * dd, 0.f);
            *(float4*)(Sv + (size_t)q * ZS + gyu * YS + gx) = s;
            if (LAST) {
                afd += (double)(s.x * oAv.x + s.y * oAv.y +
                                s.z * oAv.z + s.w * oAv.w);
                afs += (double)(s.x + s.y + s.z + s.w);
            }
        }
    };

    // ---- prologue: A(z0-4..z0+2), E1(z0-3..z0), E2(z0-2) ----
    stA(z0 - 4); stA(z0 - 3); stA(z0 - 2);
    __syncthreads();
    e1c(z0 - 3);
    stA(z0 - 1);
    __syncthreads();
    e1c(z0 - 2);
    stA(z0);
    __syncthreads();
    e1c(z0 - 1);
    stA(z0 + 1);
    __syncthreads();
    e1c(z0);
    {
        float4 dummy = ZERO4;
        e2u1(z0 - 2, ZERO4, dummy);          /* upd auto-skipped (p < z0) */
    }
    stA(z0 + 2);
    __syncthreads();

    // ---- main loop: one barrier per step ----
    for (int z = z0; z <= z1 + 4; ++z) {
        const bool doStage = (z <= z1);
        float4 st0 = PINF4, st1 = PINF4;
        if (doStage) {
            st0 = ldA(z + 3, lr);
            if (16 + lr < R3A) st1 = ldA(z + 3, 16 + lr);
        }
        float4 skN = ZERO4;
        if (!FIRST && z < z1 && uactU)
            skN = *(const float4*)(Sv + (size_t)z * ZS + gyu * YS + gx);
        float4 oN = ZERO4;
        if (LAST) {
            int zo = z - 4;
            if (zo >= z0 && zo < z1 && uactU)
                oN = *(const float4*)(Ov + (size_t)zo * ZS + gyu * YS + gx);
        }

        if (z + 1 <= z1 + 2 && z + 1 < NZ) e1c(z + 1);

        float4 spnew = ZERO4, srnew = ZERO4;
        e2u1(z - 1, skA, spnew);
        e3u2(z - 3, sq2, srnew);
        u3(z - 5, sr2, oA);

        if (doStage && c < 14) {
            int s = SLOT5(z + 3);
            As[s][lr][c] = st0;
            if (16 + lr < R3A) As[s][16 + lr][c] = st1;
        }
        __syncthreads();
        skA = skN; sq2 = sq1; sq1 = spnew; sr2 = sr1; sr1 = srnew; oA = oN;
    }

    // ---- LAST: block reduction + atomics ----
    if (LAST) {
        __syncthreads();
#pragma unroll
        for (int off = 32; off > 0; off >>= 1) {
            afd += __shfl_down(afd, off, 64);
            afs += __shfl_down(afs, off, 64);
        }
        double* sc = (double*)&As[0][0][0];
        int lane = tid & 63, wid = tid >> 6;
        if (lane == 0) { sc[wid * 2] = afd; sc[wid * 2 + 1] = afs; }
        __syncthreads();
        if (tid == 0) {
            double fd = sc[0] + sc[2] + sc[4] + sc[6];
            double fs = sc[1] + sc[3] + sc[5] + sc[7];
            if (v < 2) { atomicAdd(&sums[0], fd); atomicAdd(&sums[1], fs); }
            else       { atomicAdd(&sums[2], fd); atomicAdd(&sums[3], fs); }
        }
    }
}

__global__ void final_kernel(const double* __restrict__ sums,
                             float* __restrict__ out) {
    if (threadIdx.x == 0 && blockIdx.x == 0) {
        const double SM = 1e-5;
        double tprec = (sums[0] + SM) / (sums[1] + SM);
        double tsens = (sums[2] + SM) / (sums[3] + SM);
        double cl = 2.0 * tprec * tsens / (tprec + tsens + SM);
        out[0] = (float)(1.0 - cl);
    }
}

extern "C" void kernel_launch(void* const* d_in, const int* in_sizes, int n_in,
                              void* d_out, int out_size, void* d_ws, size_t ws_size,
                              hipStream_t stream) {
    const float* pred = (const float*)d_in[0];
    const float* target = (const float*)d_in[1];
    float* out = (float*)d_out;

    float* W0 = (float*)d_ws;
    float* W1 = W0 + NTOT;
    float* skel = W1 + NTOT;
    double* sums = (double*)(skel + NTOT);

    hipMemsetAsync(sums, 0, 4 * sizeof(double), stream);

    dim3 g3(NX / TX, NY / TY3, NV * 2);      /* 4 x 16 x 8 = 512 = 2/CU */

    /* 17 launches x 3 rounds = 51 rounds exactly */
    fused3_kernel<true, false><<<g3, 256, 0, stream>>>(pred, target, W0, W0,
                                                       skel, sums);
    float* A = W0;
    float* B = W1;
    for (int j = 1; j < 16; ++j) {
        fused3_kernel<false, false><<<g3, 256, 0, stream>>>(pred, target, A, B,
                                                            skel, sums);
        float* t = A; A = B; B = t;
    }
    fused3_kernel<false, true><<<g3, 256, 0, stream>>>(pred, target, A, B,
                                                       skel, sums);

    final_kernel<<<1, 64, 0, stream>>>(sums, out);
}

// Round 8
// 2448.500 us; speedup vs baseline: 1.2541x; 1.2541x over previous
//
#include <hip/hip_runtime.h>
#include <math.h>

#define NX 192
#define NY 192
#define NZ 96
#define NV 4
#define VOL (NZ * NY * NX)      /* 3,538,944 */
#define NTOT (NV * VOL)         /* 14,155,776 */
#define YS NX
#define ZS (NY * NX)

/* ---- single-round (LAST) kernel geometry — round-3 verified ---- */
#define TX 48
#define TY 16
#define ZCH 24
#define NG 14
#define AROWS (TY + 4)
#define EROWS (TY + 2)
#define AJOBS (AROWS * NG)
#define EJOBS (EROWS * NG)
#define UJOBS (TY * (TX / 4))

/* ---- double-round kernel geometry — round-6 verified ---- */
#define TY2 12
#define ZCH2 32
#define R2A 18                   /* A rows: halo 3 */
#define R2E1 16                  /* E1 rows: halo 2 */
#define R2E2 14                  /* E2 rows: halo 1 */

struct __align__(8) Half4 { _Float16 x, y, z, w; };

__device__ __forceinline__ float4 h4tof4(Half4 h) {
    return make_float4((float)h.x, (float)h.y, (float)h.z, (float)h.w);
}
__device__ __forceinline__ Half4 f4toh4(float4 f) {
    Half4 h;
    h.x = (_Float16)f.x; h.y = (_Float16)f.y;
    h.z = (_Float16)f.z; h.w = (_Float16)f.w;
    return h;
}

__device__ __forceinline__ float4 min4(float4 a, float4 b) {
    return make_float4(fminf(a.x, b.x), fminf(a.y, b.y),
                       fminf(a.z, b.z), fminf(a.w, b.w));
}
__device__ __forceinline__ float4 max4(float4 a, float4 b) {
    return make_float4(fmaxf(a.x, b.x), fmaxf(a.y, b.y),
                       fmaxf(a.z, b.z), fmaxf(a.w, b.w));
}
// per-element max of 3-windows over cells [a, b.x..b.w, c]
__device__ __forceinline__ float4 win3max(float a, float4 b, float c) {
    return make_float4(fmaxf(fmaxf(a, b.x), b.y),
                       fmaxf(fmaxf(b.x, b.y), b.z),
                       fmaxf(fmaxf(b.y, b.z), b.w),
                       fmaxf(fmaxf(b.z, b.w), c));
}

// ---------------- double-round kernel (round-6 verified structure) ----------
// Skewed pipeline, 1 barrier/step: E1(z+1), {E2+upd1}(z-1), upd2(z-3).
// FIRST: A read comes straight from pred/target channel 1 (f32), skel read
// skipped (treated as 0). Otherwise A is the fp16 ping-pong buffer.
// E output always written fp16.
template<bool FIRST>
__global__ __launch_bounds__(256, 3) void fused2_kernel(
    const float* __restrict__ pred, const float* __restrict__ target,
    const _Float16* __restrict__ Ain, _Float16* __restrict__ Eout,
    float* __restrict__ skel)
{
    __shared__ float4 As[5][R2A][NG];
    __shared__ float4 E1s[5][R2E1][NG];
    __shared__ float4 E2s[4][R2E2][NG];

    const int tid = threadIdx.x;
    const int lr  = tid >> 4;               /* row lane 0..15 */
    const int c   = tid & 15;               /* col group 0..15 (0..13 real) */
    const int cc  = (c < 14) ? c : 13;
    const int sr  = tid / 14;               /* stage row 0..18 (252 active) */
    const int sg  = tid - sr * 14;

    const int x0 = blockIdx.x * TX;
    const int y0 = blockIdx.y * TY2;
    const int v  = blockIdx.z / 3;
    const int ch = blockIdx.z % 3;
    const int z0 = ch * ZCH2;
    const int z1 = z0 + ZCH2;

    const float* Af = nullptr;
    const _Float16* Ah = nullptr;
    if (FIRST) Af = ((v < 2) ? pred : target) + (size_t)((v & 1) * 2 + 1) * VOL;
    else       Ah = Ain + (size_t)v * VOL;
    _Float16* Ev = Eout + (size_t)v * VOL;
    float*    Sv = skel + (size_t)v * VOL;

    const float4 PINF4 = make_float4(INFINITY, INFINITY, INFINITY, INFINITY);
    const float4 NINF4 = make_float4(-INFINITY, -INFINITY, -INFINITY, -INFINITY);
    const float4 ZERO4 = make_float4(0.f, 0.f, 0.f, 0.f);

    const bool xlo = (x0 == 0);
    const bool xhi = (x0 + TX == NX);

    const int  gys  = y0 - 3 + sr;
    const int  gxs  = x0 - 4 + 4 * sg;
    const bool stIn = (sr < R2A) && (gys >= 0) && (gys < NY) &&
                      (gxs >= 0) && (gxs < NX);

    const int  gx   = x0 - 4 + 4 * c;
    const bool gxin = (c < 14) && (gx >= 0) && (gx < NX);
    const int  gyu  = y0 + lr - 1;          /* update-cell row */
    const bool uAct = (lr >= 1 && lr <= 12 && c >= 1 && c <= 12);

    auto stageLoad = [&](int za) -> float4 {
        float4 val = PINF4;
        if (stIn && za >= 0 && za < NZ) {
            if (FIRST)
                val = *(const float4*)(Af + (size_t)za * ZS + gys * YS + gxs);
            else
                val = h4tof4(*(const Half4*)(Ah + (size_t)za * ZS + gys * YS + gxs));
        }
        return val;
    };
    auto stageWrite = [&](int za, float4 val) {
        if (sr < R2A) As[(za + 5) % 5][sr][sg] = val;
    };

    auto e1compute = [&](int zp) {          /* E1 plane zp, rows 0..15 */
        const int s_c = (zp + 5) % 5;
        const int s_m = (zp + 4) % 5;
        const int s_p = (zp + 6) % 5;
        const bool hp = (zp + 1 < NZ);
        const int ar = lr + 1;
        float4 cen = As[s_c][ar][cc];
        float4 ylo = As[s_c][ar - 1][cc];
        float4 yhi = As[s_c][ar + 1][cc];
        float4 zlo = As[s_m][ar][cc];
        float4 zhi = hp ? As[s_p][ar][cc] : PINF4;
        float lw = __shfl_up(cen.w, 1);
        float rx = __shfl_down(cen.x, 1);
        if (c == 0) lw = INFINITY;
        float4 m = min4(cen, make_float4(lw, cen.x, cen.y, cen.z));
        m = min4(m, make_float4(cen.y, cen.z, cen.w, rx));
        m = min4(m, min4(ylo, yhi));
        m = min4(m, min4(zlo, zhi));
        const int gy = y0 - 2 + lr;
        if (zp < 0 || gy < 0 || gy >= NY || !gxin) m = PINF4;
        if (c < 14) E1s[s_c][lr][c] = m;
    };

    // ---- prologue: A(z0-3..z0+2), E1(z0-2..z0) ----
    stageWrite(z0 - 3, stageLoad(z0 - 3));
    stageWrite(z0 - 2, stageLoad(z0 - 2));
    stageWrite(z0 - 1, stageLoad(z0 - 1));
    stageWrite(z0,     stageLoad(z0));
    stageWrite(z0 + 1, stageLoad(z0 + 1));
    __syncthreads();
    e1compute(z0 - 2);
    e1compute(z0 - 1);
    __syncthreads();
    stageWrite(z0 + 2, stageLoad(z0 + 2));
    e1compute(z0);
    __syncthreads();

    float4 skA = ZERO4, sq1 = ZERO4, sq2 = ZERO4;

    // ---- main loop: one barrier per step ----
    for (int z = z0; z <= z1 + 2; ++z) {
        /* issue global loads early: next A plane + skel for plane z */
        const bool doStage = (z <= z1 - 1);
        float4 stv = doStage ? stageLoad(z + 3) : PINF4;
        float4 skN = ZERO4;
        if (!FIRST && z < z1 && uAct)
            skN = *(const float4*)(Sv + (size_t)z * ZS + gyu * YS + gx);

        /* E1(z+1) */
        if (z + 1 <= z1 + 1 && z + 1 < NZ) e1compute(z + 1);

        /* merged E2(p) + upd1(p), p = z-1 */
        const int p = z - 1;
        const bool doE2 = (p >= 0) && (p <= z1) && (p < NZ);
        const bool doU1 = (p >= z0) && (p < z1);
        float4 spnew = ZERO4;
        if (doE2 || doU1) {
            const int s0 = (p + 4) % 5;     /* E1 plane p-1 */
            const int s1 = (p + 5) % 5;     /* E1 plane p   */
            const int s2 = (p + 6) % 5;     /* E1 plane p+1 */
            const bool zok0 = (p - 1 >= 0);
            const bool zok2 = (p + 1 < NZ);
            const int r = (lr < R2E2) ? lr : (R2E2 - 1);
            float4 e00 = E1s[s0][r][cc], e01 = E1s[s0][r + 1][cc], e02 = E1s[s0][r + 2][cc];
            float4 e10 = E1s[s1][r][cc], e11 = E1s[s1][r + 1][cc], e12 = E1s[s1][r + 2][cc];
            float4 e20 = E1s[s2][r][cc], e21 = E1s[s2][r + 1][cc], e22 = E1s[s2][r + 2][cc];

            /* ---- E2 erode (plane p, row gy = y0-1+lr) ---- */
            {
                float4 zhiE = zok2 ? e21 : PINF4;
                float lwE = __shfl_up(e11.w, 1);
                float rxE = __shfl_down(e11.x, 1);
                if (c == 0) lwE = INFINITY;
                float4 m2 = min4(e11, make_float4(lwE, e11.x, e11.y, e11.z));
                m2 = min4(m2, make_float4(e11.y, e11.z, e11.w, rxE));
                m2 = min4(m2, min4(e10, e12));
                m2 = min4(m2, min4(e01, zhiE));
                const int gyE = y0 - 1 + lr;
                bool oob = (gyE < 0) || (gyE >= NY) || !gxin;
                float4 m2st = oob ? NINF4 : m2;
                if (lr < R2E2 && c < 14) {
                    E2s[(p + 4) % 4][lr][c] = m2st;
                    if (p >= z0 && p < z1 && lr >= 1 && lr <= 12 && c >= 1 && c <= 12)
                        *(Half4*)(Ev + (size_t)p * ZS + gyE * YS + gx) = f4toh4(m2);
                }
            }

            /* ---- upd1: delta = relu(A(p) - dilate(E1)(p)) ---- */
            if (doU1) {
                float4 d00 = zok0 ? e00 : NINF4;
                float4 d01 = zok0 ? e01 : NINF4;
                float4 d02 = zok0 ? e02 : NINF4;
                float4 d20 = zok2 ? e20 : NINF4;
                float4 d21 = zok2 ? e21 : NINF4;
                float4 d22 = zok2 ? e22 : NINF4;
                bool oy0 = (y0 - 2 + r < 0) || (y0 - 2 + r >= NY);
                bool oy1 = (y0 - 1 + r < 0) || (y0 - 1 + r >= NY);
                bool oy2 = (y0 + r >= NY);
                float4 zm0 = oy0 ? NINF4 : max4(max4(d00, e10), d20);
                float4 zm1 = oy1 ? NINF4 : max4(max4(d01, e11), d21);
                float4 zm2 = oy2 ? NINF4 : max4(max4(d02, e12), d22);
                float lw0 = __shfl_up(zm0.w, 1), rx0 = __shfl_down(zm0.x, 1);
                float lw1 = __shfl_up(zm1.w, 1), rx1 = __shfl_down(zm1.x, 1);
                float lw2 = __shfl_up(zm2.w, 1), rx2 = __shfl_down(zm2.x, 1);
                if (xlo && c == 1)  { lw0 = -INFINITY; lw1 = -INFINITY; lw2 = -INFINITY; }
                if (xhi && c == 12) { rx0 = -INFINITY; rx1 = -INFINITY; rx2 = -INFINITY; }
                float4 dil = win3max(lw0, zm0, rx0);
                dil = max4(dil, win3max(lw1, zm1, rx1));
                dil = max4(dil, win3max(lw2, zm2, rx2));
                float4 a = As[s1][lr + 2][cc];
                float4 s = skA;
                float dd;
                dd = fmaxf(a.x - dil.x, 0.f); s.x += fmaxf(dd - s.x * dd, 0.f);
                dd = fmaxf(a.y - dil.y, 0.f); s.y += fmaxf(dd - s.y * dd, 0.f);
                dd = fmaxf(a.z - dil.z, 0.f); s.z += fmaxf(dd - s.z * dd, 0.f);
                dd = fmaxf(a.w - dil.w, 0.f); s.w += fmaxf(dd - s.w * dd, 0.f);
                spnew = s;
            }
        }

        /* ---- upd2(q): delta = relu(E1(q) - dilate(E2)(q)), q = z-3 ---- */
        const int q = z - 3;
        if (q >= z0 && q < z1) {
            const int t0s = (q + 3) % 4;
            const int t1s = (q + 4) % 4;
            const int t2s = (q + 5) % 4;
            const bool qok0 = (q - 1 >= 0);
            const bool qok2 = (q + 1 < NZ);
            const int rb = (lr >= 1) ? ((lr <= 12) ? lr - 1 : 11) : 0;
            float4 f00 = E2s[t0s][rb][cc], f01 = E2s[t0s][rb + 1][cc], f02 = E2s[t0s][rb + 2][cc];
            float4 f10 = E2s[t1s][rb][cc], f11 = E2s[t1s][rb + 1][cc], f12 = E2s[t1s][rb + 2][cc];
            float4 f20 = E2s[t2s][rb][cc], f21 = E2s[t2s][rb + 1][cc], f22 = E2s[t2s][rb + 2][cc];
            if (!qok0) { f00 = NINF4; f01 = NINF4; f02 = NINF4; }
            if (!qok2) { f20 = NINF4; f21 = NINF4; f22 = NINF4; }
            float4 zq0 = max4(max4(f00, f10), f20);
            float4 zq1 = max4(max4(f01, f11), f21);
            float4 zq2 = max4(max4(f02, f12), f22);
            float lw0 = __shfl_up(zq0.w, 1), rx0 = __shfl_down(zq0.x, 1);
            float lw1 = __shfl_up(zq1.w, 1), rx1 = __shfl_down(zq1.x, 1);
            float lw2 = __shfl_up(zq2.w, 1), rx2 = __shfl_down(zq2.x, 1);
            float4 dil = win3max(lw0, zq0, rx0);
            dil = max4(dil, win3max(lw1, zq1, rx1));
            dil = max4(dil, win3max(lw2, zq2, rx2));
            const int ra = (lr + 1 < R2E1) ? lr + 1 : (R2E1 - 1);
            float4 a = E1s[(q + 5) % 5][ra][cc];
            float4 s = sq2;
            float dd;
            dd = fmaxf(a.x - dil.x, 0.f); s.x += fmaxf(dd - s.x * dd, 0.f);
            dd = fmaxf(a.y - dil.y, 0.f); s.y += fmaxf(dd - s.y * dd, 0.f);
            dd = fmaxf(a.z - dil.z, 0.f); s.z += fmaxf(dd - s.z * dd, 0.f);
            dd = fmaxf(a.w - dil.w, 0.f); s.w += fmaxf(dd - s.w * dd, 0.f);
            if (uAct)
                *(float4*)(Sv + (size_t)q * ZS + gyu * YS + gx) = s;
        }

        /* commit staged A plane */
        if (doStage) stageWrite(z + 3, stv);

        __syncthreads();
        sq2 = sq1; sq1 = spnew; skA = skN;
    }
}

// ---------------- LAST single-round kernel (round 50 + fused reduction) -----
// Round-3 verified structure; A read fp16, no E write, skel write + in-register
// sum accumulation -> block reduce -> device atomics.
__global__ __launch_bounds__(256, 3) void fused_last_kernel(
    const _Float16* __restrict__ Ain,
    const float* __restrict__ pred, const float* __restrict__ target,
    float* __restrict__ skel, double* __restrict__ sums)
{
    __shared__ float4 As[4][AROWS][NG];
    __shared__ float4 Es[3][EROWS][NG];
    __shared__ float4 Ms[EROWS][NG];
    __shared__ double sred[8];

    const int tid = threadIdx.x;
    const int x0 = blockIdx.x * TX;
    const int y0 = blockIdx.y * TY;
    const int v  = blockIdx.z >> 2;
    const int z0 = (blockIdx.z & 3) * ZCH;
    const int z1 = z0 + ZCH;

    const _Float16* Av = Ain + (size_t)v * VOL;
    float* Sv = skel + (size_t)v * VOL;
    const float* Ov = ((v < 2) ? target : pred) + (size_t)((v & 1) * 2 + 1) * VOL;

    const float4 PINF4 = make_float4(INFINITY, INFINITY, INFINITY, INFINITY);
    const float4 NINF4 = make_float4(-INFINITY, -INFINITY, -INFINITY, -INFINITY);
    const float4 ZERO4 = make_float4(0.f, 0.f, 0.f, 0.f);

    const int ur  = tid / (TX / 4);
    const int ugp = tid - ur * (TX / 4);

    auto stageA = [&](int z) {
        int slot = (z + 8) & 3;
        float4* dst = &As[slot][0][0];
        if (z < 0 || z >= NZ) {
            for (int j = tid; j < AJOBS; j += 256) dst[j] = PINF4;
        } else {
            const _Float16* P = Av + (size_t)z * ZS;
            for (int j = tid; j < AJOBS; j += 256) {
                int r = j / NG, g = j - r * NG;
                int gy = y0 - 2 + r;
                int gx0 = x0 - 4 + 4 * g;
                float4 val = PINF4;
                if (gy >= 0 && gy < NY && gx0 >= 0 && gx0 < NX)
                    val = h4tof4(*(const Half4*)(P + gy * YS + gx0));
                dst[j] = val;
            }
        }
    };

    auto eplane = [&](int z) {
        int es = (z + 9) % 3;
        float4* dst = &Es[es][0][0];
        if (z < 0 || z >= NZ) {
            for (int j = tid; j < EJOBS; j += 256) dst[j] = NINF4;
            return;
        }
        const int sc = (z + 8) & 3;
        const int sm = (z + 7) & 3;
        const int sp = (z + 9) & 3;
        for (int j = tid; j < EJOBS; j += 256) {
            int r = j / NG, g = j - r * NG;
            float4 c  = As[sc][r + 1][g];
            float4 yl = As[sc][r][g];
            float4 yh = As[sc][r + 2][g];
            float4 zl = As[sm][r + 1][g];
            float4 zh = As[sp][r + 1][g];
            float pw = (g > 0)      ? As[sc][r + 1][g - 1].w : INFINITY;
            float nx = (g < NG - 1) ? As[sc][r + 1][g + 1].x : INFINITY;
            float4 xl = make_float4(pw, c.x, c.y, c.z);
            float4 xr = make_float4(c.y, c.z, c.w, nx);
            float4 m = min4(c, xl);
            m = min4(m, xr);
            m = min4(m, yl);
            m = min4(m, yh);
            m = min4(m, zl);
            m = min4(m, zh);
            int gy = y0 - 1 + r;
            int gx0 = x0 - 4 + 4 * g;
            if (gy < 0 || gy >= NY || gx0 < 0 || gx0 >= NX) m = NINF4;
            dst[j] = m;
        }
    };

    stageA(z0 - 2); stageA(z0 - 1); stageA(z0); stageA(z0 + 1);
    __syncthreads();
    eplane(z0 - 1);
    eplane(z0);
    __syncthreads();
    stageA(z0 + 2);
    __syncthreads();

    double afd = 0.0, afs = 0.0;

    for (int z = z0; z < z1; ++z) {
        float4 oCur = ZERO4;
        if (tid < UJOBS)
            oCur = *(const float4*)(Ov + (size_t)z * ZS +
                                    (size_t)(y0 + ur) * YS + (x0 + ugp * 4));
        stageA(z + 3);
        eplane(z + 1);
        __syncthreads();
        {
            const float4* e0 = &Es[(z + 8) % 3][0][0];
            const float4* e1 = &Es[(z + 9) % 3][0][0];
            const float4* e2 = &Es[(z + 10) % 3][0][0];
            float4* mm = &Ms[0][0];
            for (int j = tid; j < EJOBS; j += 256)
                mm[j] = max4(max4(e0[j], e1[j]), e2[j]);
        }
        __syncthreads();
        if (tid < UJOBS) {
            int g = ugp + 1;
            float4 d = NINF4;
#pragma unroll
            for (int dy = 0; dy < 3; ++dy) {
                float a  = Ms[ur + dy][g - 1].w;
                float4 b = Ms[ur + dy][g];
                float cx = Ms[ur + dy][g + 1].x;
                d = max4(d, win3max(a, b, cx));
            }
            float4 av = As[(z + 8) & 3][ur + 2][g];
            float4 delta = make_float4(fmaxf(av.x - d.x, 0.0f),
                                       fmaxf(av.y - d.y, 0.0f),
                                       fmaxf(av.z - d.z, 0.0f),
                                       fmaxf(av.w - d.w, 0.0f));
            size_t gi = (size_t)z * ZS + (size_t)(y0 + ur) * YS + (x0 + ugp * 4);
            float4* sp4 = (float4*)(Sv + gi);
            float4 s = *sp4;
            s.x += fmaxf(delta.x - s.x * delta.x, 0.0f);
            s.y += fmaxf(delta.y - s.y * delta.y, 0.0f);
            s.z += fmaxf(delta.z - s.z * delta.z, 0.0f);
            s.w += fmaxf(delta.w - s.w * delta.w, 0.0f);
            *sp4 = s;
            afd += (double)(s.x * oCur.x + s.y * oCur.y +
                            s.z * oCur.z + s.w * oCur.w);
            afs += (double)(s.x + s.y + s.z + s.w);
        }
        __syncthreads();
    }

    /* block reduction + atomics */
#pragma unroll
    for (int off = 32; off > 0; off >>= 1) {
        afd += __shfl_down(afd, off, 64);
        afs += __shfl_down(afs, off, 64);
    }
    int lane = tid & 63, wid = tid >> 6;
    if (lane == 0) { sred[wid * 2] = afd; sred[wid * 2 + 1] = afs; }
    __syncthreads();
    if (tid == 0) {
        double fd = sred[0] + sred[2] + sred[4] + sred[6];
        double fs = sred[1] + sred[3] + sred[5] + sred[7];
        if (v < 2) { atomicAdd(&sums[0], fd); atomicAdd(&sums[1], fs); }
        else       { atomicAdd(&sums[2], fd); atomicAdd(&sums[3], fs); }
    }
}

__global__ void final_kernel(const double* __restrict__ sums,
                             float* __restrict__ out) {
    if (threadIdx.x == 0 && blockIdx.x == 0) {
        const double SM = 1e-5;
        double tprec = (sums[0] + SM) / (sums[1] + SM);
        double tsens = (sums[2] + SM) / (sums[3] + SM);
        double cl = 2.0 * tprec * tsens / (tprec + tsens + SM);
        out[0] = (float)(1.0 - cl);
    }
}

extern "C" void kernel_launch(void* const* d_in, const int* in_sizes, int n_in,
                              void* d_out, int out_size, void* d_ws, size_t ws_size,
                              hipStream_t stream) {
    const float* pred = (const float*)d_in[0];
    const float* target = (const float*)d_in[1];
    float* out = (float*)d_out;

    _Float16* H0 = (_Float16*)d_ws;
    _Float16* H1 = H0 + NTOT;
    float* skel = (float*)(H1 + NTOT);
    double* sums = (double*)(skel + NTOT);

    hipMemsetAsync(sums, 0, 4 * sizeof(double), stream);

    dim3 dgrid(NX / TX, NY / TY2, NV * 3);   /* 4 x 16 x 12 = 768 = 3/CU */
    dim3 fgrid(NX / TX, NY / TY, NV * 4);    /* 4 x 12 x 16 = 768 = 3/CU */

    /* rounds 0,1: FIRST (reads pred/target channels directly, no skel read) */
    fused2_kernel<true><<<dgrid, 256, 0, stream>>>(pred, target, H0, H0, skel);
    /* rounds 2..49: 24 double launches on fp16 ping-pong */
    _Float16* A = H0;
    _Float16* B = H1;
    for (int j = 0; j < 24; ++j) {
        fused2_kernel<false><<<dgrid, 256, 0, stream>>>(pred, target, A, B, skel);
        _Float16* t = A; A = B; B = t;
    }
    /* round 50: single-round + fused global reduction */
    fused_last_kernel<<<fgrid, 256, 0, stream>>>(A, pred, target, skel, sums);

    final_kernel<<<1, 64, 0, stream>>>(sums, out);
}

// Round 9
// 1810.375 us; speedup vs baseline: 1.6961x; 1.3525x over previous
//
#include <hip/hip_runtime.h>
#include <math.h>

#define NX 192
#define NY 192
#define NZ 96
#define NV 4
#define VOL (NZ * NY * NX)      /* 3,538,944 */
#define NTOT (NV * VOL)         /* 14,155,776 */
#define YS NX
#define ZS (NY * NX)

/* ---- single-round (LAST) kernel geometry — round-3 verified ---- */
#define TX 48
#define TY 16
#define ZCH 24
#define NG 14
#define AROWS (TY + 4)
#define EROWS (TY + 2)
#define AJOBS (AROWS * NG)
#define EJOBS (EROWS * NG)
#define UJOBS (TY * (TX / 4))

/* ---- double-round kernel geometry (fp16 LDS) ---- */
#define TY2 12
#define ZCH2 16                  /* 6 z-chunks -> grid 1536 = 6 blocks/CU */
#define R2A 18                   /* A rows: halo 3 */
#define R2E1 16                  /* E1 rows: halo 2 */
#define R2E2 14                  /* E2 rows: halo 1 */

#define SLOT5(x) (((x) + 100) % 5)
#define SLOT4(x) (((x) + 100) % 4)

#define HINF  0x7C00u
#define HNINF 0xFC00u

typedef _Float16 h2v __attribute__((ext_vector_type(2)));

struct __align__(8) H4u { unsigned lo, hi; };   /* 4 fp16: e0(low16 of lo)..e3 */

__device__ __forceinline__ h2v h2_of(unsigned u) { return __builtin_bit_cast(h2v, u); }
__device__ __forceinline__ unsigned u_of(h2v h) { return __builtin_bit_cast(unsigned, h); }

__device__ __forceinline__ H4u h4min(H4u a, H4u b) {
    H4u r;
    r.lo = u_of(__builtin_elementwise_min(h2_of(a.lo), h2_of(b.lo)));
    r.hi = u_of(__builtin_elementwise_min(h2_of(a.hi), h2_of(b.hi)));
    return r;
}
__device__ __forceinline__ H4u h4max(H4u a, H4u b) {
    H4u r;
    r.lo = u_of(__builtin_elementwise_max(h2_of(a.lo), h2_of(b.lo)));
    r.hi = u_of(__builtin_elementwise_max(h2_of(a.hi), h2_of(b.hi)));
    return r;
}
/* [p, e0, e1, e2] : left-neighbor vector (p16 = prev element, low 16 bits) */
__device__ __forceinline__ H4u shl1(H4u c, unsigned p16) {
    H4u r;
    r.lo = (c.lo << 16) | (p16 & 0xFFFFu);
    r.hi = (c.hi << 16) | (c.lo >> 16);
    return r;
}
/* [e1, e2, e3, n] : right-neighbor vector */
__device__ __forceinline__ H4u shr1(H4u c, unsigned n16) {
    H4u r;
    r.lo = (c.lo >> 16) | (c.hi << 16);
    r.hi = (c.hi >> 16) | ((n16 & 0xFFFFu) << 16);
    return r;
}
__device__ __forceinline__ H4u f4_to_h4(float4 f) {
    h2v a, b;
    a[0] = (_Float16)f.x; a[1] = (_Float16)f.y;
    b[0] = (_Float16)f.z; b[1] = (_Float16)f.w;
    H4u r; r.lo = u_of(a); r.hi = u_of(b); return r;
}
__device__ __forceinline__ float4 h4_to_f4(H4u h) {
    h2v a = h2_of(h.lo), b = h2_of(h.hi);
    return make_float4((float)a[0], (float)a[1], (float)b[0], (float)b[1]);
}

__device__ __forceinline__ float4 min4(float4 a, float4 b) {
    return make_float4(fminf(a.x, b.x), fminf(a.y, b.y),
                       fminf(a.z, b.z), fminf(a.w, b.w));
}
__device__ __forceinline__ float4 max4(float4 a, float4 b) {
    return make_float4(fmaxf(a.x, b.x), fmaxf(a.y, b.y),
                       fmaxf(a.z, b.z), fmaxf(a.w, b.w));
}
__device__ __forceinline__ float4 win3max(float a, float4 b, float c) {
    return make_float4(fmaxf(fmaxf(a, b.x), b.y),
                       fmaxf(fmaxf(b.x, b.y), b.z),
                       fmaxf(fmaxf(b.y, b.z), b.w),
                       fmaxf(fmaxf(b.z, b.w), c));
}

// ---------------- double-round kernel, fp16 LDS --------------------------
// Round-8-verified skewed pipeline (1 barrier/step): E1(z+1), {E2+upd1}(z-1),
// upd2(z-3).  All morphology in packed fp16 (exact for min/max); skel math f32.
template<bool FIRST>
__global__ __launch_bounds__(256, 6) void fused2_kernel(
    const float* __restrict__ pred, const float* __restrict__ target,
    const _Float16* __restrict__ Ain, _Float16* __restrict__ Eout,
    float* __restrict__ skel)
{
    __shared__ H4u As[5][R2A][NG];
    __shared__ H4u E1s[5][R2E1][NG];
    __shared__ H4u E2s[4][R2E2][NG];

    const int tid = threadIdx.x;
    const int lr  = tid >> 4;               /* row lane 0..15 */
    const int c   = tid & 15;               /* col group 0..15 (0..13 real) */
    const int cc  = (c < 14) ? c : 13;
    const int sr  = tid / 14;               /* stage row 0..18 (252 active) */
    const int sg  = tid - sr * 14;

    const int x0 = blockIdx.x * TX;
    const int y0 = blockIdx.y * TY2;
    const int v  = blockIdx.z / 6;
    const int ch = blockIdx.z % 6;
    const int z0 = ch * ZCH2;
    const int z1 = z0 + ZCH2;

    const float* Af = nullptr;
    const _Float16* Ah = nullptr;
    if (FIRST) Af = ((v < 2) ? pred : target) + (size_t)((v & 1) * 2 + 1) * VOL;
    else       Ah = Ain + (size_t)v * VOL;
    _Float16* Ev = Eout + (size_t)v * VOL;
    float*    Sv = skel + (size_t)v * VOL;

    const H4u HP4 = { 0x7C007C00u, 0x7C007C00u };   /* +inf x4 */
    const H4u HN4 = { 0xFC00FC00u, 0xFC00FC00u };   /* -inf x4 */
    const float4 ZERO4 = make_float4(0.f, 0.f, 0.f, 0.f);

    const bool xlo = (x0 == 0);
    const bool xhi = (x0 + TX == NX);

    const int  gys  = y0 - 3 + sr;
    const int  gxs  = x0 - 4 + 4 * sg;
    const bool stIn = (sr < R2A) && (gys >= 0) && (gys < NY) &&
                      (gxs >= 0) && (gxs < NX);

    const int  gx   = x0 - 4 + 4 * c;
    const bool gxin = (c < 14) && (gx >= 0) && (gx < NX);
    const int  gyu  = y0 + lr - 1;          /* update-cell row */
    const bool uAct = (lr >= 1 && lr <= 12 && c >= 1 && c <= 12);

    auto stageLoad = [&](int za) -> H4u {
        H4u val = HP4;
        if (stIn && za >= 0 && za < NZ) {
            if (FIRST)
                val = f4_to_h4(*(const float4*)(Af + (size_t)za * ZS + gys * YS + gxs));
            else
                val = *(const H4u*)(Ah + (size_t)za * ZS + gys * YS + gxs);
        }
        return val;
    };
    auto stageWrite = [&](int za, H4u val) {
        if (sr < R2A) As[SLOT5(za)][sr][sg] = val;
    };

    auto e1compute = [&](int zp) {          /* E1 plane zp, rows 0..15 */
        const int s_c = SLOT5(zp);
        const int s_m = SLOT5(zp - 1);
        const int s_p = SLOT5(zp + 1);
        const bool hp = (zp + 1 < NZ);
        const int ar = lr + 1;
        H4u cen = As[s_c][ar][cc];
        H4u ylo = As[s_c][ar - 1][cc];
        H4u yhi = As[s_c][ar + 1][cc];
        H4u zlo = As[s_m][ar][cc];
        H4u zhi = hp ? As[s_p][ar][cc] : HP4;
        unsigned lw = __shfl_up(cen.hi, 1) >> 16;
        unsigned rx = __shfl_down(cen.lo, 1) & 0xFFFFu;
        if (c == 0) lw = HINF;
        H4u m = h4min(cen, shl1(cen, lw));
        m = h4min(m, shr1(cen, rx));
        m = h4min(m, h4min(ylo, yhi));
        m = h4min(m, h4min(zlo, zhi));
        const int gy = y0 - 2 + lr;
        if (zp < 0 || gy < 0 || gy >= NY || !gxin) m = HP4;
        if (c < 14) E1s[s_c][lr][c] = m;
    };

    // ---- prologue: A(z0-3..z0+2), E1(z0-2..z0) ----
    stageWrite(z0 - 3, stageLoad(z0 - 3));
    stageWrite(z0 - 2, stageLoad(z0 - 2));
    stageWrite(z0 - 1, stageLoad(z0 - 1));
    stageWrite(z0,     stageLoad(z0));
    stageWrite(z0 + 1, stageLoad(z0 + 1));
    __syncthreads();
    e1compute(z0 - 2);
    e1compute(z0 - 1);
    __syncthreads();
    stageWrite(z0 + 2, stageLoad(z0 + 2));
    e1compute(z0);
    __syncthreads();

    float4 skA = ZERO4, sq1 = ZERO4, sq2 = ZERO4;

    // ---- main loop: one barrier per step ----
    for (int z = z0; z <= z1 + 2; ++z) {
        /* issue global loads early: next A plane + skel for plane z */
        const bool doStage = (z <= z1 - 1);
        H4u stv = doStage ? stageLoad(z + 3) : HP4;
        float4 skN = ZERO4;
        if (!FIRST && z < z1 && uAct)
            skN = *(const float4*)(Sv + (size_t)z * ZS + gyu * YS + gx);

        /* E1(z+1) */
        if (z + 1 <= z1 + 1 && z + 1 < NZ) e1compute(z + 1);

        /* merged E2(p) + upd1(p), p = z-1 */
        const int p = z - 1;
        const bool doE2 = (p >= 0) && (p <= z1) && (p < NZ);
        const bool doU1 = (p >= z0) && (p < z1);
        float4 spnew = ZERO4;
        if (doE2 || doU1) {
            const int s0 = SLOT5(p - 1);
            const int s1 = SLOT5(p);
            const int s2 = SLOT5(p + 1);
            const bool zok0 = (p - 1 >= 0);
            const bool zok2 = (p + 1 < NZ);
            const int r = (lr < R2E2) ? lr : (R2E2 - 1);
            H4u e00 = E1s[s0][r][cc], e01 = E1s[s0][r + 1][cc], e02 = E1s[s0][r + 2][cc];
            H4u e10 = E1s[s1][r][cc], e11 = E1s[s1][r + 1][cc], e12 = E1s[s1][r + 2][cc];
            H4u e20 = E1s[s2][r][cc], e21 = E1s[s2][r + 1][cc], e22 = E1s[s2][r + 2][cc];

            /* ---- E2 erode (plane p, row gy = y0-1+lr) ---- */
            {
                H4u zhiE = zok2 ? e21 : HP4;
                unsigned lwE = __shfl_up(e11.hi, 1) >> 16;
                unsigned rxE = __shfl_down(e11.lo, 1) & 0xFFFFu;
                if (c == 0) lwE = HINF;
                H4u m2 = h4min(e11, shl1(e11, lwE));
                m2 = h4min(m2, shr1(e11, rxE));
                m2 = h4min(m2, h4min(e10, e12));
                m2 = h4min(m2, h4min(e01, zhiE));
                const int gyE = y0 - 1 + lr;
                bool oob = (gyE < 0) || (gyE >= NY) || !gxin;
                H4u m2st = oob ? HN4 : m2;
                if (lr < R2E2 && c < 14) {
                    E2s[SLOT4(p)][lr][c] = m2st;
                    if (p >= z0 && p < z1 && lr >= 1 && lr <= 12 && c >= 1 && c <= 12)
                        *(H4u*)(Ev + (size_t)p * ZS + gyE * YS + gx) = m2;
                }
            }

            /* ---- upd1: delta = relu(A(p) - dilate(E1)(p)) ---- */
            if (doU1) {
                H4u r0 = h4max(zok0 ? e00 : HN4, h4max(e10, zok2 ? e20 : HN4));
                H4u r1 = h4max(zok0 ? e01 : HN4, h4max(e11, zok2 ? e21 : HN4));
                H4u r2 = h4max(zok0 ? e02 : HN4, h4max(e12, zok2 ? e22 : HN4));
                bool oy0 = (y0 - 2 + r < 0) || (y0 - 2 + r >= NY);
                bool oy1 = (y0 - 1 + r < 0) || (y0 - 1 + r >= NY);
                bool oy2 = (y0 + r >= NY);
                if (oy0) r0 = HN4;
                if (oy1) r1 = HN4;
                if (oy2) r2 = HN4;
                H4u vm = h4max(r0, h4max(r1, r2));
                unsigned lw = __shfl_up(vm.hi, 1) >> 16;
                unsigned rx = __shfl_down(vm.lo, 1) & 0xFFFFu;
                if (xlo && c == 1)  lw = HNINF;
                if (xhi && c == 12) rx = HNINF;
                if (uAct) {
                    H4u dilh = h4max(h4max(shl1(vm, lw), vm), shr1(vm, rx));
                    float4 dil = h4_to_f4(dilh);
                    float4 a = h4_to_f4(As[s1][lr + 2][cc]);
                    float4 s = skA;
                    float dd;
                    dd = fmaxf(a.x - dil.x, 0.f); s.x += fmaxf(dd - s.x * dd, 0.f);
                    dd = fmaxf(a.y - dil.y, 0.f); s.y += fmaxf(dd - s.y * dd, 0.f);
                    dd = fmaxf(a.z - dil.z, 0.f); s.z += fmaxf(dd - s.z * dd, 0.f);
                    dd = fmaxf(a.w - dil.w, 0.f); s.w += fmaxf(dd - s.w * dd, 0.f);
                    spnew = s;
                }
            }
        }

        /* ---- upd2(q): delta = relu(E1(q) - dilate(E2)(q)), q = z-3 ---- */
        const int q = z - 3;
        if (q >= z0 && q < z1) {
            const int t0s = SLOT4(q - 1);
            const int t1s = SLOT4(q);
            const int t2s = SLOT4(q + 1);
            const bool qok0 = (q - 1 >= 0);
            const bool qok2 = (q + 1 < NZ);
            const int rb = (lr >= 1) ? ((lr <= 12) ? lr - 1 : 11) : 0;
            H4u f00 = E2s[t0s][rb][cc], f01 = E2s[t0s][rb + 1][cc], f02 = E2s[t0s][rb + 2][cc];
            H4u f10 = E2s[t1s][rb][cc], f11 = E2s[t1s][rb + 1][cc], f12 = E2s[t1s][rb + 2][cc];
            H4u f20 = E2s[t2s][rb][cc], f21 = E2s[t2s][rb + 1][cc], f22 = E2s[t2s][rb + 2][cc];
            if (!qok0) { f00 = HN4; f01 = HN4; f02 = HN4; }
            if (!qok2) { f20 = HN4; f21 = HN4; f22 = HN4; }
            H4u zq0 = h4max(f00, h4max(f10, f20));
            H4u zq1 = h4max(f01, h4max(f11, f21));
            H4u zq2 = h4max(f02, h4max(f12, f22));
            H4u vm = h4max(zq0, h4max(zq1, zq2));
            unsigned lw = __shfl_up(vm.hi, 1) >> 16;
            unsigned rx = __shfl_down(vm.lo, 1) & 0xFFFFu;
            /* E2s stores -inf pads: no x/y overrides needed */
            if (uAct) {
                H4u dilh = h4max(h4max(shl1(vm, lw), vm), shr1(vm, rx));
                float4 dil = h4_to_f4(dilh);
                const int ra = (lr + 1 < R2E1) ? lr + 1 : (R2E1 - 1);
                float4 a = h4_to_f4(E1s[SLOT5(q)][ra][cc]);
                float4 s = sq2;
                float dd;
                dd = fmaxf(a.x - dil.x, 0.f); s.x += fmaxf(dd - s.x * dd, 0.f);
                dd = fmaxf(a.y - dil.y, 0.f); s.y += fmaxf(dd - s.y * dd, 0.f);
                dd = fmaxf(a.z - dil.z, 0.f); s.z += fmaxf(dd - s.z * dd, 0.f);
                dd = fmaxf(a.w - dil.w, 0.f); s.w += fmaxf(dd - s.w * dd, 0.f);
                *(float4*)(Sv + (size_t)q * ZS + gyu * YS + gx) = s;
            }
        }

        /* commit staged A plane */
        if (doStage) stageWrite(z + 3, stv);

        __syncthreads();
        sq2 = sq1; sq1 = spnew; skA = skN;
    }
}

// ---------------- LAST single-round kernel (round 50 + fused reduction) -----
__global__ __launch_bounds__(256, 3) void fused_last_kernel(
    const _Float16* __restrict__ Ain,
    const float* __restrict__ pred, const float* __restrict__ target,
    float* __restrict__ skel, double* __restrict__ sums)
{
    __shared__ float4 As[4][AROWS][NG];
    __shared__ float4 Es[3][EROWS][NG];
    __shared__ float4 Ms[EROWS][NG];
    __shared__ double sred[8];

    const int tid = threadIdx.x;
    const int x0 = blockIdx.x * TX;
    const int y0 = blockIdx.y * TY;
    const int v  = blockIdx.z >> 2;
    const int z0 = (blockIdx.z & 3) * ZCH;
    const int z1 = z0 + ZCH;

    const _Float16* Av = Ain + (size_t)v * VOL;
    float* Sv = skel + (size_t)v * VOL;
    const float* Ov = ((v < 2) ? target : pred) + (size_t)((v & 1) * 2 + 1) * VOL;

    const float4 PINF4 = make_float4(INFINITY, INFINITY, INFINITY, INFINITY);
    const float4 NINF4 = make_float4(-INFINITY, -INFINITY, -INFINITY, -INFINITY);
    const float4 ZERO4 = make_float4(0.f, 0.f, 0.f, 0.f);

    const int ur  = tid / (TX / 4);
    const int ugp = tid - ur * (TX / 4);

    auto stageA = [&](int z) {
        int slot = (z + 8) & 3;
        float4* dst = &As[slot][0][0];
        if (z < 0 || z >= NZ) {
            for (int j = tid; j < AJOBS; j += 256) dst[j] = PINF4;
        } else {
            const _Float16* P = Av + (size_t)z * ZS;
            for (int j = tid; j < AJOBS; j += 256) {
                int r = j / NG, g = j - r * NG;
                int gy = y0 - 2 + r;
                int gx0 = x0 - 4 + 4 * g;
                float4 val = PINF4;
                if (gy >= 0 && gy < NY && gx0 >= 0 && gx0 < NX)
                    val = h4_to_f4(*(const H4u*)(P + gy * YS + gx0));
                dst[j] = val;
            }
        }
    };

    auto eplane = [&](int z) {
        int es = (z + 9) % 3;
        float4* dst = &Es[es][0][0];
        if (z < 0 || z >= NZ) {
            for (int j = tid; j < EJOBS; j += 256) dst[j] = NINF4;
            return;
        }
        const int sc = (z + 8) & 3;
        const int sm = (z + 7) & 3;
        const int sp = (z + 9) & 3;
        for (int j = tid; j < EJOBS; j += 256) {
            int r = j / NG, g = j - r * NG;
            float4 c  = As[sc][r + 1][g];
            float4 yl = As[sc][r][g];
            float4 yh = As[sc][r + 2][g];
            float4 zl = As[sm][r + 1][g];
            float4 zh = As[sp][r + 1][g];
            float pw = (g > 0)      ? As[sc][r + 1][g - 1].w : INFINITY;
            float nx = (g < NG - 1) ? As[sc][r + 1][g + 1].x : INFINITY;
            float4 xl = make_float4(pw, c.x, c.y, c.z);
            float4 xr = make_float4(c.y, c.z, c.w, nx);
            float4 m = min4(c, xl);
            m = min4(m, xr);
            m = min4(m, yl);
            m = min4(m, yh);
            m = min4(m, zl);
            m = min4(m, zh);
            int gy = y0 - 1 + r;
            int gx0 = x0 - 4 + 4 * g;
            if (gy < 0 || gy >= NY || gx0 < 0 || gx0 >= NX) m = NINF4;
            dst[j] = m;
        }
    };

    stageA(z0 - 2); stageA(z0 - 1); stageA(z0); stageA(z0 + 1);
    __syncthreads();
    eplane(z0 - 1);
    eplane(z0);
    __syncthreads();
    stageA(z0 + 2);
    __syncthreads();

    double afd = 0.0, afs = 0.0;

    for (int z = z0; z < z1; ++z) {
        float4 oCur = ZERO4;
        if (tid < UJOBS)
            oCur = *(const float4*)(Ov + (size_t)z * ZS +
                                    (size_t)(y0 + ur) * YS + (x0 + ugp * 4));
        stageA(z + 3);
        eplane(z + 1);
        __syncthreads();
        {
            const float4* e0 = &Es[(z + 8) % 3][0][0];
            const float4* e1 = &Es[(z + 9) % 3][0][0];
            const float4* e2 = &Es[(z + 10) % 3][0][0];
            float4* mm = &Ms[0][0];
            for (int j = tid; j < EJOBS; j += 256)
                mm[j] = max4(max4(e0[j], e1[j]), e2[j]);
        }
        __syncthreads();
        if (tid < UJOBS) {
            int g = ugp + 1;
            float4 d = NINF4;
#pragma unroll
            for (int dy = 0; dy < 3; ++dy) {
                float a  = Ms[ur + dy][g - 1].w;
                float4 b = Ms[ur + dy][g];
                float cx = Ms[ur + dy][g + 1].x;
                d = max4(d, win3max(a, b, cx));
            }
            float4 av = As[(z + 8) & 3][ur + 2][g];
            float4 delta = make_float4(fmaxf(av.x - d.x, 0.0f),
                                       fmaxf(av.y - d.y, 0.0f),
                                       fmaxf(av.z - d.z, 0.0f),
                                       fmaxf(av.w - d.w, 0.0f));
            size_t gi = (size_t)z * ZS + (size_t)(y0 + ur) * YS + (x0 + ugp * 4);
            float4* sp4 = (float4*)(Sv + gi);
            float4 s = *sp4;
            s.x += fmaxf(delta.x - s.x * delta.x, 0.0f);
            s.y += fmaxf(delta.y - s.y * delta.y, 0.0f);
            s.z += fmaxf(delta.z - s.z * delta.z, 0.0f);
            s.w += fmaxf(delta.w - s.w * delta.w, 0.0f);
            *sp4 = s;
            afd += (double)(s.x * oCur.x + s.y * oCur.y +
                            s.z * oCur.z + s.w * oCur.w);
            afs += (double)(s.x + s.y + s.z + s.w);
        }
        __syncthreads();
    }

#pragma unroll
    for (int off = 32; off > 0; off >>= 1) {
        afd += __shfl_down(afd, off, 64);
        afs += __shfl_down(afs, off, 64);
    }
    int lane = tid & 63, wid = tid >> 6;
    if (lane == 0) { sred[wid * 2] = afd; sred[wid * 2 + 1] = afs; }
    __syncthreads();
    if (tid == 0) {
        double fd = sred[0] + sred[2] + sred[4] + sred[6];
        double fs = sred[1] + sred[3] + sred[5] + sred[7];
        if (v < 2) { atomicAdd(&sums[0], fd); atomicAdd(&sums[1], fs); }
        else       { atomicAdd(&sums[2], fd); atomicAdd(&sums[3], fs); }
    }
}

__global__ void final_kernel(const double* __restrict__ sums,
                             float* __restrict__ out) {
    if (threadIdx.x == 0 && blockIdx.x == 0) {
        const double SM = 1e-5;
        double tprec = (sums[0] + SM) / (sums[1] + SM);
        double tsens = (sums[2] + SM) / (sums[3] + SM);
        double cl = 2.0 * tprec * tsens / (tprec + tsens + SM);
        out[0] = (float)(1.0 - cl);
    }
}

extern "C" void kernel_launch(void* const* d_in, const int* in_sizes, int n_in,
                              void* d_out, int out_size, void* d_ws, size_t ws_size,
                              hipStream_t stream) {
    const float* pred = (const float*)d_in[0];
    const float* target = (const float*)d_in[1];
    float* out = (float*)d_out;

    _Float16* H0 = (_Float16*)d_ws;
    _Float16* H1 = H0 + NTOT;
    float* skel = (float*)(H1 + NTOT);
    double* sums = (double*)(skel + NTOT);

    hipMemsetAsync(sums, 0, 4 * sizeof(double), stream);

    dim3 dgrid(NX / TX, NY / TY2, NV * 6);   /* 4 x 16 x 24 = 1536 = 6/CU */
    dim3 fgrid(NX / TX, NY / TY, NV * 4);    /* 4 x 12 x 16 = 768 = 3/CU */

    /* rounds 0,1: FIRST (reads pred/target channels directly, no skel read) */
    fused2_kernel<true><<<dgrid, 256, 0, stream>>>(pred, target, H0, H0, skel);
    /* rounds 2..49: 24 double launches on fp16 ping-pong */
    _Float16* A = H0;
    _Float16* B = H1;
    for (int j = 0; j < 24; ++j) {
        fused2_kernel<false><<<dgrid, 256, 0, stream>>>(pred, target, A, B, skel);
        _Float16* t = A; A = B; B = t;
    }
    /* round 50: single-round + fused global reduction */
    fused_last_kernel<<<fgrid, 256, 0, stream>>>(A, pred, target, skel, sums);

    final_kernel<<<1, 64, 0, stream>>>(sums, out);
}